// Round 5
// baseline (61.499 us; speedup 1.0000x reference)
//
#include <hip/hip_runtime.h>
#include <hip/hip_bf16.h>
#include <stdint.h>

// KAN layer: out[n,o] = sum_j w[o,j] * spline(x[n,j]; coeffs[o,j,:]) + bias[o]
// N=1024, D_IN=128, D_OUT=128, K=8, Catmull-Rom, uniform grid [-1,1].
// fp32 in/out (proven R1/R2/R4).
//
// R13: 2-kernel split = +3.05us (graph node ~3us). ONE launch only.
// R14: pack-shift basis + dealiased sC (-1 barrier) = -1.26us. KEPT.
// R15: zero-staging = +5.15us. 256MB ws-poison fill evicts L2/L3 -> kernel
//   always cold; scattered loads put ~900cy HBM latency on the MFMA path.
//   Kernel is COLD-LATENCY + LAUNCH-OVERHEAD bound. Staging stays.
// R16: XCD pinning + issue-early = -0.18us (noise-level; inputs are only
//   ~1.1MB so locality was never the cost). KEPT but lever exhausted.
//
// R17 (this): FAT TILE 16n x 32o, grid 256 = exactly 1 block/CU.
//   Two co-resident 16x16-tile blocks ran in lockstep (same barriers), so
//   dual-block overlap bought ~nothing; it cost 2x redundant phase-1 and
//   2x waves. Now per-CU: phase-1 tasks 8192->6144 (basis redundancy
//   8x->4x), waves 8192->4096 (half the ramp), barriers 4->2, same cold
//   bytes (~144KB/CU). LDS 32+64+16 = 112KB, 1 block/CU, 16 waves.
//   Wave = (o-half ot, K-eighth kg): 4 MFMA steps; 8-way sC reduce by
//   512 threads. Numerics-bearing code identical (absmax 0.015625).
//
// MFMA 16x16x32 bf16 (R5..R16-verified): A/B-frag lane (mo=lane&15,
// q=lane>>4) holds [mo][k=32S+8q+kk]; C/D: col=lane&15, row=(lane>>4)*4+reg.

#define DIN 128
#define DOUT 128
#define KTOT 1024

typedef unsigned int u32;
typedef unsigned long long u64;
typedef unsigned short u16;
typedef __attribute__((ext_vector_type(8))) short bf16x8;
typedef __attribute__((ext_vector_type(4))) float f32x4;

union H8 { u16 s[8]; uint4 v; };

__device__ __forceinline__ u16 f2b(float f) {
    union { __hip_bfloat16 h; u16 u; } c;
    c.h = __float2bfloat16(f);   // RNE
    return c.u;
}

__global__ __launch_bounds__(1024, 4) void kan_fused(
    const float* __restrict__ x, const float* __restrict__ coeffs,
    const float* __restrict__ weights, const float* __restrict__ bias,
    float* __restrict__ out)
{
    __shared__ __align__(16) u16 sBas[16 * KTOT];   // 32 KB (16 n-rows)
    __shared__ __align__(16) u16 sWp [32 * KTOT];   // 64 KB (32 o-rows)
    __shared__ __align__(16) float sC[16 * 256];    // 16 KB partials

    const int tid  = threadIdx.x;
    const int wave = tid >> 6;                      // 0..15
    const int lane = tid & 63;
    const int wg = blockIdx.x;                      // 0..255 (1D)
    const int n0 = (wg >> 2) * 16;                  // 64 n-tiles
    const int o0 = (wg & 3) * 32;                   // 4 o-super-tiles

    // ---- Issue ALL global loads first (overlap cold-HBM latency with
    //      the spline VALU chain). Static indices only (rule #20). ----
    float xv0, xv1;
    float wv[4];
    float4 ca[4], cb[4];
    xv0 = x[n0 * DIN + tid];
    xv1 = x[n0 * DIN + tid + 1024];
    #pragma unroll
    for (int it = 0; it < 4; ++it) {
        const int task = tid + it * 1024;           // o_loc*128 + j
        wv[it] = weights[o0 * DIN + task];
        ca[it] = *(const float4*)(coeffs + o0 * KTOT + task * 8);
        cb[it] = *(const float4*)(coeffs + o0 * KTOT + task * 8 + 4);
    }

    // ---- Phase 1a: basis tile. 2048 tasks (row,j), pack-shift build ----
    #pragma unroll
    for (int it = 0; it < 2; ++it) {
        const int task = tid + it * 1024;           // row*128 + j
        const int row = task >> 7;
        const int j = task & 127;
        float xv = it == 0 ? xv0 : xv1;
        xv = fminf(fmaxf(xv, -1.0f), 1.0f);
        const float t = (xv + 1.0f) * 3.5f;         // h = 2/7
        int idx = (int)t; idx = idx > 6 ? 6 : idx;  // t>=0: trunc==floor
        const float u = t - (float)idx;
        const float u2 = u * u, u3 = u2 * u;
        const float b0 = 0.5f * (-u3 + 2.0f * u2 - u);
        const float b1 = 0.5f * (3.0f * u3 - 5.0f * u2 + 2.0f);
        const float b2 = 0.5f * (-3.0f * u3 + 4.0f * u2 + u);
        const float b3 = 0.5f * (u3 - u2);
        // Contiguous-run form of the clipped scatter (R14-verified,
        // fp32 merges first, bit-identical to accumulate-then-convert):
        //   idx==0: [b0+b1, b2, b3] at slot 0
        //   1..5 :  [b0, b1, b2, b3] at slot idx-1
        //   idx==6: [b0, b1, b2+b3] at slot 5 (b3 shifts out of 128b)
        const bool e0 = (idx == 0), e6 = (idx == 6);
        const float m0 = e0 ? b0 + b1 : b0;
        const float m1 = e0 ? b2 : b1;
        const float m2 = e0 ? b3 : (e6 ? b2 + b3 : b2);
        const float m3 = e0 ? 0.0f : b3;
        const u32 lo32 = (u32)f2b(m0) | ((u32)f2b(m1) << 16);
        const u32 hi32 = (u32)f2b(m2) | ((u32)f2b(m3) << 16);
        const u64 q64 = ((u64)hi32 << 32) | lo32;
        const int sh = e0 ? 0 : (idx - 1) * 16;     // 0..80 bits
        unsigned __int128 v = (unsigned __int128)q64 << sh;
        uint4 stv;
        stv.x = (u32)v;
        stv.y = (u32)(v >> 32);
        stv.z = (u32)(v >> 64);
        stv.w = (u32)(v >> 96);
        const int uu = j ^ (row & 7);               // swizzled 16B unit
        *(uint4*)(sBas + row * KTOT + uu * 8) = stv;
    }

    // ---- Phase 1b: W' tile. 4096 tasks (o_loc,j), loads in flight ----
    #pragma unroll
    for (int it = 0; it < 4; ++it) {
        const int task = tid + it * 1024;           // o_loc*128 + j
        const int o = task >> 7;                    // 0..31
        const int j = task & 127;
        const float w_ = wv[it];
        const float4 c0 = ca[it];
        const float4 c1 = cb[it];
        H8 h;
        h.s[0] = f2b(c0.x * w_); h.s[1] = f2b(c0.y * w_);
        h.s[2] = f2b(c0.z * w_); h.s[3] = f2b(c0.w * w_);
        h.s[4] = f2b(c1.x * w_); h.s[5] = f2b(c1.y * w_);
        h.s[6] = f2b(c1.z * w_); h.s[7] = f2b(c1.w * w_);
        const int uu = j ^ (o & 7);
        *(uint4*)(sWp + o * KTOT + uu * 8) = h.v;
    }
    __syncthreads();

    // ---- Phase 2: pure LDS MFMA. wave = (o-half ot, K-eighth kg) ----
    const int mo = lane & 15;
    const int q  = lane >> 4;
    const int ot = wave >> 3;                       // 0..1 (o sub-tile)
    const int kg = wave & 7;                        // 0..7 (K-eighth)
    const int sw = mo & 7;                          // read-side swizzle
    // B row = ot*16+mo; (ot*16+mo)&7 == mo&7, so sw applies to both.
    const u16* bRow = sWp + (ot * 16 + mo) * KTOT;
    f32x4 acc = {0.0f, 0.0f, 0.0f, 0.0f};
    #pragma unroll
    for (int s = 0; s < 4; ++s) {
        const int S = kg * 4 + s;                   // global K-step 0..31
        const int uu = (S * 4 + q) ^ sw;            // 16B unit
        bf16x8 af = *(const bf16x8*)(sBas + mo * KTOT + uu * 8);
        bf16x8 bf = *(const bf16x8*)(bRow + uu * 8);
        acc = __builtin_amdgcn_mfma_f32_16x16x32_bf16(af, bf, acc, 0, 0, 0);
    }
    // sC is its own LDS region -> no barrier needed before writing it.

    // ---- Phase 3: 8-way reduce per o-half + bias + store ----
    #pragma unroll
    for (int r = 0; r < 4; ++r)
        sC[wave * 256 + (q * 4 + r) * 16 + mo] = acc[r];
    __syncthreads();

    if (tid < 512) {
        const int ot2 = tid >> 8;                   // o-half
        const int idx = tid & 255;                  // rr*16 + cc
        const int row = idx >> 4, col = idx & 15;
        float v = sC[ot2 * 2048 + idx];
        #pragma unroll
        for (int k = 1; k < 8; ++k) v += sC[ot2 * 2048 + k * 256 + idx];
        const int oc = o0 + ot2 * 16 + col;
        out[(n0 + row) * DOUT + oc] = v + bias[oc];
    }
}

extern "C" void kernel_launch(void* const* d_in, const int* in_sizes, int n_in,
                              void* d_out, int out_size, void* d_ws, size_t ws_size,
                              hipStream_t stream) {
    const float* x       = (const float*)d_in[0];
    const float* coeffs  = (const float*)d_in[1];
    const float* weights = (const float*)d_in[2];
    const float* bias    = (const float*)d_in[3];
    float* out = (float*)d_out;
    const int N = in_sizes[0] / DIN;                // 1024
    dim3 grid((N / 16) * (DOUT / 32));              // 64 x 4 = 256 blocks
    kan_fused<<<grid, 1024, 0, stream>>>(x, coeffs, weights, bias, out);
}